// Round 9
// baseline (420.148 us; speedup 1.0000x reference)
//
#include <hip/hip_runtime.h>
#include <hip/hip_bf16.h>

#define TPB 256
#define NB 512          // partition buckets
#define MAXW 256        // max nodes per bucket (width = ceil(n/NB) must be <= MAXW)
#define P1K 32          // edges per thread per chunk
#define CH (TPB*P1K)    // 8192 edges per chunk
#define NSHADOW 8       // fallback path
#define NTEAM 8
#define TEAMS_PER 256

// ============================ chunk-sorted CSR build ============================

__global__ void k_zero512(int* __restrict__ bsize){
  bsize[threadIdx.x] = 0;
}

// per chunk: LDS counting sort by dst-bucket; write temp[cb..cb+ce) contiguously
// (coalesced full lines, single XCD). Also write chunk-local bucket starts to bhist
// and accumulate global bucket sizes.
__global__ void k_phase1_sort(const int* __restrict__ src, const int* __restrict__ dst,
                              int E, int n, int nchunk,
                              unsigned* __restrict__ temp, int* __restrict__ bhist,
                              int* __restrict__ bsize, int sbits){
  __shared__ int lh[NB];        // bucket counts
  __shared__ int lcur[NB];      // rank cursors (start offsets)
  __shared__ int sc[TPB];       // pair-sum scan
  __shared__ unsigned stage[CH];
  int t = threadIdx.x;
  for(int c = blockIdx.x; c < nchunk; c += gridDim.x){
    int cb = c * CH;
    int ce = E - cb; if(ce > CH) ce = CH;
    lh[t] = 0; lh[t+256] = 0;
    __syncthreads();
    int d[P1K];
    #pragma unroll
    for(int i = 0; i < P1K; i++){
      int e = cb + i*TPB + t;
      d[i] = (e < E) ? dst[e] : -1;
      if(d[i] >= 0){
        int b = (int)(((long long)d[i] * NB) / n);
        atomicAdd(&lh[b], 1);
      }
    }
    __syncthreads();
    // exclusive scan over 512 bins: thread t owns bins 2t, 2t+1
    int a0 = lh[2*t], a1 = lh[2*t+1];
    int ps = a0 + a1;
    sc[t] = ps;
    __syncthreads();
    for(int off=1; off<TPB; off<<=1){
      int add = (t>=off) ? sc[t-off] : 0;
      __syncthreads();
      sc[t] += add;
      __syncthreads();
    }
    int base = sc[t] - ps;                 // exclusive over pairs
    lcur[2*t]   = base;
    lcur[2*t+1] = base + a0;
    bhist[(size_t)c*NB + 2*t]   = base;    // chunk-local starts
    bhist[(size_t)c*NB + 2*t+1] = base + a0;
    if(a0 > 0) atomicAdd(&bsize[2*t],   a0);
    if(a1 > 0) atomicAdd(&bsize[2*t+1], a1);
    __syncthreads();
    // rank + stage (LDS counting sort)
    #pragma unroll
    for(int i = 0; i < P1K; i++){
      if(d[i] >= 0){
        int e = cb + i*TPB + t;
        int b = (int)(((long long)d[i] * NB) / n);
        int lo = (int)(((long long)n * b + NB - 1) / NB);
        int r = atomicAdd(&lcur[b], 1);
        stage[r] = (unsigned)src[e] | ((unsigned)(d[i] - lo) << sbits);
      }
    }
    __syncthreads();
    // contiguous coalesced write-out
    for(int i = t; i < ce; i += TPB)
      temp[cb + i] = stage[i];
    __syncthreads();
  }
}

// single block: exclusive scan of bsize -> bucket_base
__global__ void k_bscan512(const int* __restrict__ bsize, int E, int* __restrict__ bucket_base){
  __shared__ int s[NB];
  int t = threadIdx.x;
  int v = bsize[t];
  s[t] = v;
  __syncthreads();
  for(int off = 1; off < NB; off <<= 1){
    int add = (t >= off) ? s[t-off] : 0;
    __syncthreads();
    s[t] += add;
    __syncthreads();
  }
  bucket_base[t] = s[t] - v;   // exclusive
  if(t == 0) bucket_base[NB] = E;
}

// per bucket (1 block): read this bucket's runs from every chunk; LDS degree histogram
// + scan -> deg,row_start,dinv,ysA; then scatter into exact csr slots via LDS cursors.
__global__ void k_bucket_build(const unsigned* __restrict__ temp, const int* __restrict__ bhist,
                               const int* __restrict__ bucket_base,
                               int E, int n, int nchunk, int sbits, unsigned smask,
                               int* __restrict__ deg, int* __restrict__ row_start,
                               float* __restrict__ dinv,
                               const float* __restrict__ x, float* __restrict__ ysA,
                               int* __restrict__ csr){
  __shared__ int hist[MAXW], scn[MAXW], cur[MAXW];
  int b = blockIdx.x;
  int lo = (int)(((long long)n * b + NB - 1) / NB);
  int hi = (int)(((long long)n * (b+1) + NB - 1) / NB);
  if(hi > n) hi = n;
  int width = hi - lo;
  int t = threadIdx.x;
  hist[t] = 0;
  __syncthreads();
  int grp = t >> 4, l16 = t & 15;   // 16 groups x 16 lanes
  for(int c = grp; c < nchunk; c += 16){
    int cb = c * CH;
    int st = bhist[(size_t)c*NB + b];
    int en = (b < NB-1) ? bhist[(size_t)c*NB + b + 1] : ((E - cb < CH) ? (E - cb) : CH);
    for(int i = st + l16; i < en; i += 16)
      atomicAdd(&hist[temp[cb + i] >> sbits], 1);
  }
  __syncthreads();
  int v = hist[t];
  scn[t] = v;
  __syncthreads();
  for(int off=1; off<MAXW; off<<=1){
    int add = (t>=off) ? scn[t-off] : 0;
    __syncthreads();
    scn[t] += add;
    __syncthreads();
  }
  int e0 = bucket_base[b];
  int rs = e0 + scn[t] - v;
  cur[t] = rs;
  if(t < width){
    int node = lo + t;
    deg[node]       = v;
    row_start[node] = rs;
    float dv = rsqrtf((float)(v + 1));   // +1 self loop
    dinv[node] = dv;
    ysA[node]  = dv * (10.f * x[node]);
  }
  __syncthreads();
  for(int c = grp; c < nchunk; c += 16){
    int cb = c * CH;
    int st = bhist[(size_t)c*NB + b];
    int en = (b < NB-1) ? bhist[(size_t)c*NB + b + 1] : ((E - cb < CH) ? (E - cb) : CH);
    for(int i = st + l16; i < en; i += 16){
      unsigned u = temp[cb + i];
      int pos = atomicAdd(&cur[u >> sbits], 1);
      csr[pos] = (int)(u & smask);
    }
  }
}

// ============================ fused gather layers ============================
// wave (64 lanes) per node; 4 nodes per 256-block

__global__ void k_gA(const int* __restrict__ csr, const int* __restrict__ row_start,
                     const int* __restrict__ deg, const float* __restrict__ dinv,
                     const float* __restrict__ ys, const float* __restrict__ W,
                     const float* __restrict__ B, float* __restrict__ y4, int n){
  int node = blockIdx.x*4 + (threadIdx.x >> 6);
  int lane = threadIdx.x & 63;
  if(node >= n) return;
  int rs = row_start[node], dg = deg[node];
  float s = 0.f;
  for(int j=lane; j<dg; j+=64) s += ys[csr[rs+j]];
  #pragma unroll
  for(int m=32; m; m>>=1) s += __shfl_xor(s, m, 64);
  if(lane == 0){
    float dv = dinv[node];
    float t  = dv * (ys[node] + s);
    float h0 = fmaxf(t*W[0]+B[0], 0.f);
    float h1 = fmaxf(t*W[1]+B[1], 0.f);
    float h2 = fmaxf(t*W[2]+B[2], 0.f);
    float h3 = fmaxf(t*W[3]+B[3], 0.f);
    *reinterpret_cast<float4*>(y4 + 4*(size_t)node) = make_float4(dv*h0, dv*h1, dv*h2, dv*h3);
  }
}

__global__ void k_gB(const int* __restrict__ csr, const int* __restrict__ row_start,
                     const int* __restrict__ deg, const float* __restrict__ dinv,
                     const float* __restrict__ y4, const float* __restrict__ W2,
                     const float* __restrict__ B2, const float* __restrict__ W3,
                     float* __restrict__ ys_out, int n){
  int node = blockIdx.x*4 + (threadIdx.x >> 6);
  int lane = threadIdx.x & 63;
  if(node >= n) return;
  int rs = row_start[node], dg = deg[node];
  float ax=0.f, ay=0.f, az=0.f, aw=0.f;
  for(int j=lane; j<dg; j+=64){
    float4 v = *reinterpret_cast<const float4*>(y4 + 4*(size_t)csr[rs+j]);
    ax += v.x; ay += v.y; az += v.z; aw += v.w;
  }
  #pragma unroll
  for(int m=32; m; m>>=1){
    ax += __shfl_xor(ax, m, 64);
    ay += __shfl_xor(ay, m, 64);
    az += __shfl_xor(az, m, 64);
    aw += __shfl_xor(aw, m, 64);
  }
  if(lane == 0){
    float dv = dinv[node];
    float4 sf = *reinterpret_cast<const float4*>(y4 + 4*(size_t)node);
    float z0 = dv*(ax+sf.x), z1 = dv*(ay+sf.y), z2 = dv*(az+sf.z), z3 = dv*(aw+sf.w);
    float s = 0.f;
    #pragma unroll
    for(int k=0;k<4;k++){
      float g = B2[k] + z0*W2[0*4+k] + z1*W2[1*4+k] + z2*W2[2*4+k] + z3*W2[3*4+k];
      g = fmaxf(g, 0.f);
      s += g * W3[k];
    }
    ys_out[node] = dv * s;
  }
}

__global__ void k_gC_mid(const int* __restrict__ csr, const int* __restrict__ row_start,
                         const int* __restrict__ deg, const float* __restrict__ dinv,
                         const float* __restrict__ ys, const float* __restrict__ B3,
                         float* __restrict__ x2, float* __restrict__ ys_out, int n){
  int node = blockIdx.x*4 + (threadIdx.x >> 6);
  int lane = threadIdx.x & 63;
  if(node >= n) return;
  int rs = row_start[node], dg = deg[node];
  float s = 0.f;
  for(int j=lane; j<dg; j+=64) s += ys[csr[rs+j]];
  #pragma unroll
  for(int m=32; m; m>>=1) s += __shfl_xor(s, m, 64);
  if(lane == 0){
    float dv = dinv[node];
    float u  = dv * (ys[node] + s) + B3[0];
    float v2 = sinf(10.f * u);
    x2[node] = v2;
    ys_out[node] = dv * v2;
  }
}

__global__ void k_gC_fin(const int* __restrict__ csr, const int* __restrict__ row_start,
                         const int* __restrict__ deg, const float* __restrict__ dinv,
                         const float* __restrict__ ys, const float* __restrict__ B3,
                         const float* __restrict__ x2, float* __restrict__ out,
                         float* __restrict__ pbuf, int n){
  int node = blockIdx.x*4 + (threadIdx.x >> 6);
  int lane = threadIdx.x & 63;
  int w = threadIdx.x >> 6;
  bool act = node < n;
  float v2 = 0.f, x3 = 0.f;
  if(act){
    int rs = row_start[node], dg = deg[node];
    float s = 0.f;
    for(int j=lane; j<dg; j+=64) s += ys[csr[rs+j]];
    #pragma unroll
    for(int m=32; m; m>>=1) s += __shfl_xor(s, m, 64);
    x3 = dinv[node] * (ys[node] + s) + B3[0];
    v2 = x2[node];
  }
  __shared__ float p2[4], p3[4];
  if(lane == 0){
    p2[w] = act ? v2 : 0.f;
    p3[w] = act ? x3 : 0.f;
    if(act)
      *reinterpret_cast<float2*>(out + 2 + 2*(size_t)node) = make_float2(v2, x3);
  }
  __syncthreads();
  if(threadIdx.x == 0){
    pbuf[2*(size_t)blockIdx.x]   = p2[0]+p2[1]+p2[2]+p2[3];
    pbuf[2*(size_t)blockIdx.x+1] = p3[0]+p3[1]+p3[2]+p3[3];
  }
}

__global__ void k_reduce_mean(const float* __restrict__ pbuf, int nb,
                              float* __restrict__ out, float invn){
  float s2 = 0.f, s3 = 0.f;
  for(int i = threadIdx.x; i < nb; i += 1024){
    s2 += pbuf[2*i];
    s3 += pbuf[2*i+1];
  }
  #pragma unroll
  for(int m=32; m; m>>=1){ s2 += __shfl_xor(s2, m, 64); s3 += __shfl_xor(s3, m, 64); }
  __shared__ float a2[16], a3[16];
  int w = threadIdx.x >> 6, lane = threadIdx.x & 63;
  if(lane == 0){ a2[w] = s2; a3[w] = s3; }
  __syncthreads();
  if(threadIdx.x == 0){
    float t2 = 0.f, t3 = 0.f;
    #pragma unroll
    for(int k=0;k<16;k++){ t2 += a2[k]; t3 += a3[k]; }
    out[0] = t2 * invn;
    out[1] = t3 * invn;
  }
}

// ============================ fallback build (round-5: shadowed deg + XCD fill) ============================

__global__ void k_zero8(int* __restrict__ degS, int m){
  int i = blockIdx.x*TPB + threadIdx.x;
  if(i < m) degS[i] = 0;
}

__global__ void k_deg8(const int* __restrict__ dst, int E, int* __restrict__ degS, int n){
  int e = blockIdx.x*TPB + threadIdx.x;
  if(e < E) atomicAdd(&degS[(size_t)(blockIdx.x & (NSHADOW-1))*(size_t)n + dst[e]], 1);
}

__global__ void k_bsum(const int* __restrict__ degS, int n, int* __restrict__ bsum){
  int i = blockIdx.x*TPB + threadIdx.x;
  int v = 0;
  if(i < n){
    #pragma unroll
    for(int s=0;s<NSHADOW;s++) v += degS[(size_t)s*(size_t)n + i];
  }
  #pragma unroll
  for(int off=32; off; off>>=1) v += __shfl_down(v, off, 64);
  __shared__ int ls[4];
  int lane = threadIdx.x & 63, w = threadIdx.x >> 6;
  if(lane == 0) ls[w] = v;
  __syncthreads();
  if(threadIdx.x == 0) bsum[blockIdx.x] = ls[0]+ls[1]+ls[2]+ls[3];
}

__global__ void k_bscan(int* __restrict__ bsum, int nb){
  __shared__ int s[1024];
  int t = threadIdx.x;
  int v = (t < nb) ? bsum[t] : 0;
  s[t] = v;
  __syncthreads();
  for(int off=1; off<1024; off<<=1){
    int add = (t >= off) ? s[t-off] : 0;
    __syncthreads();
    s[t] += add;
    __syncthreads();
  }
  if(t < nb) bsum[t] = s[t] - v;
}

__global__ void k_rowstart2(int* __restrict__ degS, const int* __restrict__ bsum, int n,
                            int* __restrict__ deg, int* __restrict__ row_start,
                            float* __restrict__ dinv,
                            const float* __restrict__ x, float* __restrict__ ysA){
  __shared__ int s[TPB];
  int i = blockIdx.x*TPB + threadIdx.x;
  int t = threadIdx.x;
  int c[NSHADOW];
  int v = 0;
  if(i < n){
    #pragma unroll
    for(int sh=0;sh<NSHADOW;sh++){ c[sh] = degS[(size_t)sh*(size_t)n + i]; v += c[sh]; }
  }
  s[t] = v;
  __syncthreads();
  for(int off=1; off<TPB; off<<=1){
    int add = (t >= off) ? s[t-off] : 0;
    __syncthreads();
    s[t] += add;
    __syncthreads();
  }
  if(i < n){
    int rs = bsum[blockIdx.x] + s[t] - v;
    deg[i]       = v;
    row_start[i] = rs;
    float dv = rsqrtf((float)(v + 1));
    dinv[i] = dv;
    ysA[i]  = dv * (10.f * x[i]);
    int base = rs;
    #pragma unroll
    for(int sh=0;sh<NSHADOW;sh++){ degS[(size_t)sh*(size_t)n + i] = base; base += c[sh]; }
  }
}

__global__ void k_fill_xcd(const int* __restrict__ src, const int* __restrict__ dst,
                           int E, int n, int* __restrict__ cursorS, int* __restrict__ csr){
  int team = blockIdx.x & (NTEAM-1);
  int tr   = blockIdx.x >> 3;
  int lo = (int)(((long long)n * team) >> 3);
  int hi = (int)(((long long)n * (team+1)) >> 3);
  int nchunk = (E + TPB - 1) / TPB;
  for(int ci = tr; ci < nchunk; ci += TEAMS_PER){
    int e = ci*TPB + threadIdx.x;
    if(e < E){
      int d = dst[e];
      if(d >= lo && d < hi){
        int sh = ci & (NSHADOW-1);
        int pos = atomicAdd(&cursorS[(size_t)sh*(size_t)n + d], 1);
        csr[pos] = src[e];
      }
    }
  }
}

// ============================ launch ============================

extern "C" void kernel_launch(void* const* d_in, const int* in_sizes, int n_in,
                              void* d_out, int out_size, void* d_ws, size_t ws_size,
                              hipStream_t stream) {
  const float* x   = (const float*)d_in[0];
  const int*   ei  = (const int*)  d_in[1];
  const float* w11 = (const float*)d_in[2];
  const float* b11 = (const float*)d_in[3];
  const float* w12 = (const float*)d_in[4];
  const float* b12 = (const float*)d_in[5];
  const float* w13 = (const float*)d_in[6];
  const float* b13 = (const float*)d_in[7];
  const float* w21 = (const float*)d_in[8];
  const float* b21 = (const float*)d_in[9];
  const float* w22 = (const float*)d_in[10];
  const float* b22 = (const float*)d_in[11];
  const float* w23 = (const float*)d_in[12];
  const float* b23 = (const float*)d_in[13];
  float* out = (float*)d_out;

  const int n = in_sizes[0];
  const int E = in_sizes[1] / 2;
  const int* src = ei;
  const int* dst = ei + E;

  const int gn  = (n + TPB - 1)/TPB;
  const int gn4 = (n + 3)/4;
  const int ge  = (E + TPB - 1)/TPB;

  float* ws = (float*)d_ws;

  // packing parameters for bucket path
  int sbits = 1; while((1 << sbits) < n && sbits < 31) sbits++;          // bits for src
  int maxw  = (n + NB - 1) / NB;
  int dbits = 1; while((1 << dbits) < maxw && dbits < 31) dbits++;       // bits for dstLocal
  unsigned smask = (sbits >= 31) ? 0x7FFFFFFFu : ((1u << sbits) - 1u);

  const int nchunk = (E + CH - 1) / CH;

  const size_t need_bucket = ((size_t)10*n + 1536 + (size_t)nchunk*NB + 2*(size_t)E + 64) * 4;
  const size_t need_r5     = ((size_t)18*n + 1024 + (size_t)E) * 4;

  if(ws_size >= need_bucket && n >= NB && maxw <= MAXW && (sbits + dbits) <= 32){
    // ---------------- chunk-sorted bucketed CSR path ----------------
    float*    y4          = ws;                               // 4n (pbuf alias later)
    float*    dinv        = ws + 4*(size_t)n;                 // n
    float*    ysA         = ws + 5*(size_t)n;                 // n
    float*    ysB         = ws + 6*(size_t)n;                 // n
    float*    x2          = ws + 7*(size_t)n;                 // n
    int*      deg         = (int*)(ws + 8*(size_t)n);         // n
    int*      row_start   = (int*)(ws + 9*(size_t)n);         // n
    int*      bucket_base = (int*)(ws + 10*(size_t)n);        // NB+1 (pad 1024)
    int*      bsize       = bucket_base + 1024;               // NB (pad 512)
    int*      bhist       = bsize + 512;                      // nchunk*NB (chunk-local starts)
    unsigned* temp        = (unsigned*)(bhist + (size_t)nchunk*NB);  // E (chunk-major, sorted)
    int*      csr         = (int*)(temp + (size_t)E);         // E
    float*    pbuf        = y4;

    int gbuild = nchunk < 8192 ? nchunk : 8192;
    k_zero512     <<<1, 512, 0, stream>>>(bsize);
    k_phase1_sort <<<gbuild, TPB, 0, stream>>>(src, dst, E, n, nchunk, temp, bhist, bsize, sbits);
    k_bscan512    <<<1, NB, 0, stream>>>(bsize, E, bucket_base);
    k_bucket_build<<<NB, TPB, 0, stream>>>(temp, bhist, bucket_base, E, n, nchunk, sbits, smask,
                                           deg, row_start, dinv, x, ysA, csr);

    // gcn #1
    k_gA    <<<gn4, TPB, 0, stream>>>(csr, row_start, deg, dinv, ysA, w11, b11, y4, n);
    k_gB    <<<gn4, TPB, 0, stream>>>(csr, row_start, deg, dinv, y4, w12, b12, w13, ysB, n);
    k_gC_mid<<<gn4, TPB, 0, stream>>>(csr, row_start, deg, dinv, ysB, b13, x2, ysA, n);
    // gcn #2
    k_gA    <<<gn4, TPB, 0, stream>>>(csr, row_start, deg, dinv, ysA, w21, b21, y4, n);
    k_gB    <<<gn4, TPB, 0, stream>>>(csr, row_start, deg, dinv, y4, w22, b22, w23, ysB, n);
    k_gC_fin<<<gn4, TPB, 0, stream>>>(csr, row_start, deg, dinv, ysB, b23, x2, out, pbuf, n);
    k_reduce_mean<<<1, 1024, 0, stream>>>(pbuf, gn4, out, 1.f/(float)n);
  } else if(ws_size >= need_r5 && gn <= 1024 && (size_t)E >= (size_t)NSHADOW*(size_t)n){
    // ---------------- round-5 CSR path (fallback) ----------------
    float* y4        = ws;
    float* dinv      = ws + 4*(size_t)n;
    float* ysA       = ws + 5*(size_t)n;
    float* ysB       = ws + 6*(size_t)n;
    float* x2        = ws + 7*(size_t)n;
    int*   deg       = (int*)(ws + 8*(size_t)n);
    int*   row_start = (int*)(ws + 9*(size_t)n);
    int*   bsum      = (int*)(ws + 10*(size_t)n);
    int*   degS      = (int*)(ws + 10*(size_t)n + 1024);
    int*   csr       = degS + 8*(size_t)n;
    float* pbuf      = y4;

    const int m8 = NSHADOW*n;
    k_zero8    <<<(m8+TPB-1)/TPB, TPB, 0, stream>>>(degS, m8);
    k_deg8     <<<ge, TPB, 0, stream>>>(dst, E, degS, n);
    k_bsum     <<<gn, TPB, 0, stream>>>(degS, n, bsum);
    k_bscan    <<<1, 1024, 0, stream>>>(bsum, gn);
    k_rowstart2<<<gn, TPB, 0, stream>>>(degS, bsum, n, deg, row_start, dinv, x, ysA);
    k_fill_xcd <<<NTEAM*TEAMS_PER, TPB, 0, stream>>>(src, dst, E, n, degS, csr);

    k_gA    <<<gn4, TPB, 0, stream>>>(csr, row_start, deg, dinv, ysA, w11, b11, y4, n);
    k_gB    <<<gn4, TPB, 0, stream>>>(csr, row_start, deg, dinv, y4, w12, b12, w13, ysB, n);
    k_gC_mid<<<gn4, TPB, 0, stream>>>(csr, row_start, deg, dinv, ysB, b13, x2, ysA, n);
    k_gA    <<<gn4, TPB, 0, stream>>>(csr, row_start, deg, dinv, ysA, w21, b21, y4, n);
    k_gB    <<<gn4, TPB, 0, stream>>>(csr, row_start, deg, dinv, y4, w22, b22, w23, ysB, n);
    k_gC_fin<<<gn4, TPB, 0, stream>>>(csr, row_start, deg, dinv, ysB, b23, x2, out, pbuf, n);
    k_reduce_mean<<<1, 1024, 0, stream>>>(pbuf, gn4, out, 1.f/(float)n);
  }
}